// Round 2
// baseline (446.203 us; speedup 1.0000x reference)
//
#include <hip/hip_runtime.h>
#include <hip/hip_bf16.h>

using bf16 = __hip_bfloat16;
typedef float float4v __attribute__((ext_vector_type(4)));
typedef __bf16 bf16x8 __attribute__((ext_vector_type(8)));
typedef unsigned short ushort4v __attribute__((ext_vector_type(4)));
typedef unsigned short ushort8v __attribute__((ext_vector_type(8)));

#define B_  4
#define L_  4096
#define D_  2048
#define DI_ 256
#define M_  (B_*L_)       // 16384 rows
#define NC  64            // scan chunks per sequence
#define LC  (L_/NC)       // 64 steps per chunk

__device__ inline float bf2f(bf16 x) { return __bfloat162float(x); }
__device__ inline bf16  f2bf(float x) { return __float2bfloat16(x); }

__device__ inline void store4bf(bf16* p, float4v v) {
    ushort4v u;
#pragma unroll
    for (int i = 0; i < 4; i++) {
        bf16 h = f2bf(v[i]);
        u[i] = *(unsigned short*)&h;
    }
    *(ushort4v*)p = u;   // single 8B store
}

__device__ inline float4v load4bf(const bf16* p) {
    ushort4v u = *(const ushort4v*)p;
    float4v v;
#pragma unroll
    for (int i = 0; i < 4; i++) v[i] = __uint_as_float(((unsigned)u[i]) << 16);
    return v;
}

__device__ inline ushort8v cvt8(float4v a, float4v b) {
    ushort8v u;
#pragma unroll
    for (int i = 0; i < 4; i++) {
        bf16 h0 = f2bf(a[i]); u[i]     = *(unsigned short*)&h0;
        bf16 h1 = f2bf(b[i]); u[i + 4] = *(unsigned short*)&h1;
    }
    return u;
}

// async global->LDS, 16B per lane. LDS dest is wave-uniform base + lane*16.
__device__ __forceinline__ void gload_lds16(const bf16* g, bf16* l) {
    __builtin_amdgcn_global_load_lds((const __attribute__((address_space(1))) void*)(g),
                                     (__attribute__((address_space(3))) void*)(l),
                                     16, 0, 0);
}

template<int N> __device__ __forceinline__ void vmwait() {
    asm volatile("s_waitcnt vmcnt(%0)" :: "n"(N) : "memory");
}
template<int N> __device__ __forceinline__ void vmwait_lgkm0() {
    asm volatile("s_waitcnt vmcnt(%0) lgkmcnt(0)" :: "n"(N) : "memory");
}
__device__ __forceinline__ void bar() {
    asm volatile("" ::: "memory");
    __builtin_amdgcn_s_barrier();
    asm volatile("" ::: "memory");
}

// ---------------------------------------------------------------------------
// Transpose+convert: in fp32 [R,C] -> out bf16 [C+obase, R] rows (weights only)
// ---------------------------------------------------------------------------
__global__ void transpose_cvt(const float* __restrict__ in, bf16* __restrict__ out,
                              int R, int C, int obase) {
    int idx = blockIdx.x * 256 + threadIdx.x;
    if (idx < R * C) {
        int r = idx / C, c = idx - r * C;
        out[(size_t)(c + obase) * R + r] = f2bf(in[idx]);
    }
}

// ---------------------------------------------------------------------------
// MFMA GEMM: C[M,N] = A[M,K] x BT[N,K].  2-deep counted-vmcnt pipeline:
//   prologue: stage tile0 -> buf0, tile1 -> buf1 (2 tiles in flight)
//   iter t:   s_waitcnt vmcnt(TOPW) [tile t landed, t+1 still in flight]
//             s_barrier ; compute(buf t&1) ; s_barrier
//             stage tile t+2 -> buf t&1        (never drains to 0 mid-loop)
// Staging via global_load_lds (16B/lane) into linear LDS [row][32k] with the
// XOR slot-swizzle via pre-swizzled GLOBAL source (slot s of row r holds
// k-slot s ^ ((r>>1)&3)); ds_read uses slot (quad ^ ((l15>>1)&3)).
// AF32 path: A fp32 reg-staged 2 tiles ahead (ping-pong fa0/fa1, 2-unrolled
// loop for static indexing), cvt+ds_write one tile ahead; derived waits:
//   top:  vmcnt(2AP+BP) lgkmcnt(0)   (B(t) landed, own A ds_write done)
//   mid:  vmcnt(2AP+2BP)             (A(t+1) regs landed; tail: vmcnt(BP))
// EPI: 0 = store bf16; 1 = delta/gate 4-way split (N=1024, aux=z);
//      2 = +fp32 residual (auxf = x), store bf16
// ---------------------------------------------------------------------------
#define BK 32

template<int TBM, int TBN, int EPI, bool AF32>
__global__ __launch_bounds__(256) void gemm_bt(const void* __restrict__ Av,
                                               const bf16* __restrict__ BT,
                                               int K, int N,
                                               bf16* __restrict__ o0, bf16* __restrict__ o1,
                                               bf16* __restrict__ o2, bf16* __restrict__ o3,
                                               const bf16* __restrict__ auxb,
                                               const float* __restrict__ auxf) {
    constexpr int MI  = TBM / 32, NI = TBN / 32, AP = TBM / 64, BP = TBN / 64;
    constexpr int ASZ = TBM * 32, BSZ = TBN * 32;   // bf16 elems per buffer
    constexpr int TOPW = AF32 ? (2 * AP + BP) : (AP + BP);
    constexpr int MIDW = 2 * AP + 2 * BP;           // AF32 only
    __shared__ __align__(16) bf16 As[2 * ASZ];
    __shared__ __align__(16) bf16 Bs[2 * BSZ];
    const int tid  = threadIdx.x;
    const int bm   = blockIdx.x, bn = blockIdx.y;
    const int lane = tid & 63, wave = tid >> 6;
    const int wm   = (wave >> 1) * (TBM / 2), wn = (wave & 1) * (TBN / 2);
    const int l15  = lane & 15, quad = lane >> 4;
    const int rsub  = lane >> 2;                      // row within a 16-row stage instr
    const int kslot = (lane & 3) ^ ((lane >> 3) & 3); // pre-swizzled global k-slot
    const int sq    = quad ^ ((l15 >> 1) & 3);        // swizzled read slot
    const int sr    = tid >> 2, scs = tid & 3;        // AF32 staging row / k-slot
    const int swslot = scs ^ ((sr >> 1) & 3);         // AF32 swizzled write slot

    float4v acc[MI][NI] = {};
    const float* Af = (const float*)Av;
    const bf16*  Ab = (const bf16*)Av;
    float4v fa0[AP][2], fa1[AP][2];

    auto stage_a = [&](int buf, int kk) {             // bf16 A via DMA (AP instrs)
#pragma unroll
        for (int p = 0; p < AP; p++) {
            int rbase = wave * (TBM / 4) + p * 16;
            gload_lds16(Ab + (size_t)(bm * TBM + rbase + rsub) * K + kk + kslot * 8,
                        As + buf * ASZ + rbase * 32 + lane * 8);
        }
    };
    auto stage_b = [&](int buf, int kk) {             // bf16 B via DMA (BP instrs)
#pragma unroll
        for (int p = 0; p < BP; p++) {
            int rbase = wave * (TBN / 4) + p * 16;
            gload_lds16(BT + (size_t)(bn * TBN + rbase + rsub) * K + kk + kslot * 8,
                        Bs + buf * BSZ + rbase * 32 + lane * 8);
        }
    };
    auto load_a_f32 = [&](float4v (&fa)[AP][2], int kk) {  // fp32 A -> regs (2*AP loads)
#pragma unroll
        for (int p = 0; p < AP; p++) {
            const float* src = Af + (size_t)(bm * TBM + p * 64 + sr) * K + kk + scs * 8;
            fa[p][0] = *(const float4v*)src;
            fa[p][1] = *(const float4v*)(src + 4);
        }
    };
    auto write_a_f32 = [&](float4v (&fa)[AP][2], int buf) {  // regs -> LDS (swizzled)
#pragma unroll
        for (int p = 0; p < AP; p++)
            *(ushort8v*)(As + buf * ASZ + (p * 64 + sr) * 32 + swslot * 8)
                = cvt8(fa[p][0], fa[p][1]);
    };
    auto compute = [&](int buf) {
        bf16x8 af[MI], bfr[NI];
#pragma unroll
        for (int mi = 0; mi < MI; mi++)
            af[mi] = *(const bf16x8*)(As + buf * ASZ + (wm + mi * 16 + l15) * 32 + sq * 8);
#pragma unroll
        for (int ni = 0; ni < NI; ni++)
            bfr[ni] = *(const bf16x8*)(Bs + buf * BSZ + (wn + ni * 16 + l15) * 32 + sq * 8);
        __builtin_amdgcn_s_setprio(1);
#pragma unroll
        for (int mi = 0; mi < MI; mi++)
#pragma unroll
            for (int ni = 0; ni < NI; ni++)
                acc[mi][ni] = __builtin_amdgcn_mfma_f32_16x16x32_bf16(
                    bfr[ni], af[mi], acc[mi][ni], 0, 0, 0);
        __builtin_amdgcn_s_setprio(0);
    };

    const int nt = K / BK;

    if constexpr (AF32) {
        // prologue: A(0)->fa0, B(0)->buf0, A(1)->fa1, B(1)->buf1; write A(0)
        load_a_f32(fa0, 0);
        stage_b(0, 0);
        load_a_f32(fa1, BK);
        stage_b(1, BK);
        vmwait<MIDW>();               // A(0) landed (B0+A1+B1 may remain)
        write_a_f32(fa0, 0);

        auto body = [&](int t, int buf, float4v (&fT)[AP][2], float4v (&fT1)[AP][2]) {
            if (t == nt - 1) vmwait_lgkm0<0>(); else vmwait_lgkm0<TOPW>();
            bar();
            compute(buf);
            bar();
            if (t + 2 < nt) {
                load_a_f32(fT, (t + 2) * BK);   // A(t+2) -> regs (parity t)
                stage_b(buf, (t + 2) * BK);     // B(t+2) -> buf (parity t)
                vmwait<MIDW>();                 // A(t+1) landed
            } else if (t + 1 < nt) {
                vmwait<BP>();                   // only B(t+1) may remain
            }
            if (t + 1 < nt) write_a_f32(fT1, buf ^ 1);
        };
        for (int t = 0; t < nt; t += 2) {       // nt is even for all our shapes
            body(t, 0, fa0, fa1);
            body(t + 1, 1, fa1, fa0);
        }
    } else {
        stage_a(0, 0);  stage_b(0, 0);
        stage_a(1, BK); stage_b(1, BK);
        for (int t = 0; t < nt; t++) {
            if (t == nt - 1) vmwait<0>(); else vmwait<TOPW>();
            bar();
            compute(t & 1);
            bar();
            if (t + 2 < nt) {
                stage_a(t & 1, (t + 2) * BK);
                stage_b(t & 1, (t + 2) * BK);
            }
        }
    }

    // Swapped layout: row(M) = l15-based, cols = quad*4 + reg (4 consecutive)
#pragma unroll
    for (int mi = 0; mi < MI; mi++) {
#pragma unroll
        for (int ni = 0; ni < NI; ni++) {
            int row = bm * TBM + wm + mi * 16 + l15;
            int col = bn * TBN + wn + ni * 16 + quad * 4;
            float4v v = acc[mi][ni];
            if (EPI == 0) {
                store4bf(o0 + (size_t)row * N + col, v);
            } else if (EPI == 1) {
                int sel = col >> 8, d = col & 255;
                bf16* dst = (sel == 0) ? o0 : (sel == 1) ? o1 : (sel == 2) ? o2 : o3;
                if (sel & 1) {   // gate = o * z
                    float4v z4 = load4bf(auxb + (size_t)row * DI_ + d);
#pragma unroll
                    for (int i = 0; i < 4; i++) v[i] *= z4[i];
                } else {         // delta = sigmoid(o)
#pragma unroll
                    for (int i = 0; i < 4; i++) v[i] = 1.f / (1.f + __expf(-v[i]));
                }
                store4bf(dst + (size_t)row * DI_ + d, v);
            } else {
                float4v r = *(const float4v*)(auxf + (size_t)row * N + col);
#pragma unroll
                for (int i = 0; i < 4; i++) v[i] += r[i];
                store4bf(o0 + (size_t)row * N + col, v);
            }
        }
    }
}

// ---------------------------------------------------------------------------
// Chunked linear-recurrence scan: h_t = delta_t * h_{t-1} + gate_t
// blockIdx.z = direction (0 fwd, 1 bwd/reversed)
// ---------------------------------------------------------------------------
__global__ __launch_bounds__(256) void scan_agg(const bf16* __restrict__ del_f,
                                                const bf16* __restrict__ gat_f,
                                                const bf16* __restrict__ del_b,
                                                const bf16* __restrict__ gat_b,
                                                float* __restrict__ aggA,
                                                float* __restrict__ aggB) {
    int c = blockIdx.x, b = blockIdx.y, dir = blockIdx.z, d = threadIdx.x;
    const bf16* delta = dir ? del_b : del_f;
    const bf16* gate  = dir ? gat_b : gat_f;
    float Ap = 1.f, h = 0.f;
    for (int i = 0; i < LC; i++) {
        int t = dir ? (L_ - 1 - (c * LC + i)) : (c * LC + i);
        size_t base = ((size_t)(b * L_ + t)) * DI_ + d;
        float dlt = bf2f(delta[base]);
        float g   = bf2f(gate[base]);
        Ap *= dlt;
        h = h * dlt + g;
    }
    size_t idx = (((size_t)dir * B_ + b) * NC + c) * DI_ + d;
    aggA[idx] = Ap;
    aggB[idx] = h;
}

__global__ void scan_mid(const float* __restrict__ aggA, const float* __restrict__ aggB,
                         float* __restrict__ Hin) {
    int b = blockIdx.x, dir = blockIdx.y, d = threadIdx.x;
    float h = 0.f;
    for (int c = 0; c < NC; c++) {
        size_t idx = (((size_t)dir * B_ + b) * NC + c) * DI_ + d;
        Hin[idx] = h;
        h = aggA[idx] * h + aggB[idx];
    }
}

__global__ __launch_bounds__(256) void scan_fix(const bf16* __restrict__ del_f,
                                                const bf16* __restrict__ gat_f,
                                                const bf16* __restrict__ del_b,
                                                const bf16* __restrict__ gat_b,
                                                const float* __restrict__ Hin,
                                                bf16* __restrict__ hcat) {
    int c = blockIdx.x, b = blockIdx.y, dir = blockIdx.z, d = threadIdx.x;
    const bf16* delta = dir ? del_b : del_f;
    const bf16* gate  = dir ? gat_b : gat_f;
    float h = Hin[(((size_t)dir * B_ + b) * NC + c) * DI_ + d];
    int colbase = dir * DI_;
    for (int i = 0; i < LC; i++) {
        int t = dir ? (L_ - 1 - (c * LC + i)) : (c * LC + i);
        size_t base = ((size_t)(b * L_ + t)) * DI_ + d;
        float dlt = bf2f(delta[base]);
        float g   = bf2f(gate[base]);
        h = h * dlt + g;
        hcat[((size_t)(b * L_ + t)) * (2 * DI_) + colbase + d] = f2bf(h);
    }
}

// ---------------------------------------------------------------------------
// LayerNorm over D=2048: reads bf16 ybuf, writes fp32 out. Fully vectorized.
// ---------------------------------------------------------------------------
__global__ __launch_bounds__(256) void ln_kernel(const bf16* __restrict__ y,
                                                 const float* __restrict__ gamma,
                                                 const float* __restrict__ beta,
                                                 float* __restrict__ outp) {
    __shared__ float ss[4], ssq[4];
    int row = blockIdx.x, tid = threadIdx.x;
    size_t base = (size_t)row * D_ + tid * 8;
    uint4 raw = *(const uint4*)(y + base);
    const unsigned short* u = (const unsigned short*)&raw;
    float v[8];
    float s = 0.f, sq = 0.f;
#pragma unroll
    for (int i = 0; i < 8; i++) {
        v[i] = __uint_as_float(((unsigned)u[i]) << 16);
        s += v[i];
        sq += v[i] * v[i];
    }
    for (int o = 32; o > 0; o >>= 1) { s += __shfl_down(s, o); sq += __shfl_down(sq, o); }
    if ((tid & 63) == 0) { ss[tid >> 6] = s; ssq[tid >> 6] = sq; }
    __syncthreads();
    float S  = ss[0] + ss[1] + ss[2] + ss[3];
    float SQ = ssq[0] + ssq[1] + ssq[2] + ssq[3];
    float mean = S * (1.f / D_);
    float var  = SQ * (1.f / D_) - mean * mean;
    float rstd = rsqrtf(var + 1e-5f);
    float4v g0 = *(const float4v*)(gamma + tid * 8);
    float4v g1 = *(const float4v*)(gamma + tid * 8 + 4);
    float4v b0 = *(const float4v*)(beta + tid * 8);
    float4v b1 = *(const float4v*)(beta + tid * 8 + 4);
    float4v r0, r1;
#pragma unroll
    for (int i = 0; i < 4; i++) {
        r0[i] = (v[i] - mean) * rstd * g0[i] + b0[i];
        r1[i] = (v[i + 4] - mean) * rstd * g1[i] + b1[i];
    }
    *(float4v*)(outp + base)     = r0;
    *(float4v*)(outp + base + 4) = r1;
}

// ---------------------------------------------------------------------------
extern "C" void kernel_launch(void* const* d_in, const int* in_sizes, int n_in,
                              void* d_out, int out_size, void* d_ws, size_t ws_size,
                              hipStream_t stream) {
    (void)in_sizes; (void)n_in; (void)out_size; (void)ws_size;
    const float* x     = (const float*)d_in[0];
    const float* W_in  = (const float*)d_in[1];
    const float* W_fwd = (const float*)d_in[2];
    const float* W_bwd = (const float*)d_in[3];
    const float* W_out = (const float*)d_in[4];
    const float* gamma = (const float*)d_in[5];
    const float* beta  = (const float*)d_in[6];
    float* out = (float*)d_out;

    char* ws = (char*)d_ws;
    size_t off = 0;
    auto alloc = [&](size_t bytes) -> char* {
        char* p = ws + off;
        off += (bytes + 255) & ~(size_t)255;
        return p;
    };
    bf16*  WinT   = (bf16*)alloc((size_t)DI_ * D_ * 2);           // [256, 2048]
    bf16*  WpT    = (bf16*)alloc((size_t)1024 * DI_ * 2);         // [1024, 256] fwd|bwd
    bf16*  WoutT  = (bf16*)alloc((size_t)D_ * 2 * DI_ * 2);       // [2048, 512]
    bf16*  z      = (bf16*)alloc((size_t)M_ * DI_ * 2);
    bf16*  del_f  = (bf16*)alloc((size_t)M_ * DI_ * 2);
    bf16*  gat_f  = (bf16*)alloc((size_t)M_ * DI_ * 2);
    bf16*  del_b  = (bf16*)alloc((size_t)M_ * DI_ * 2);
    bf16*  gat_b  = (bf16*)alloc((size_t)M_ * DI_ * 2);
    bf16*  hcat   = (bf16*)alloc((size_t)M_ * 2 * DI_ * 2);       // 16.8 MB
    bf16*  ybuf   = (bf16*)alloc((size_t)M_ * D_ * 2);            // 67 MB
    float* aggA   = (float*)alloc((size_t)2 * B_ * NC * DI_ * 4);
    float* aggB   = (float*)alloc((size_t)2 * B_ * NC * DI_ * 4);
    float* Hin    = (float*)alloc((size_t)2 * B_ * NC * DI_ * 4);

    // 1. weight transposes (fp32 -> bf16 [N,K])
    transpose_cvt<<<(D_ * DI_ + 255) / 256, 256, 0, stream>>>(W_in, WinT, D_, DI_, 0);
    transpose_cvt<<<(DI_ * 2 * DI_ + 255) / 256, 256, 0, stream>>>(W_fwd, WpT, DI_, 2 * DI_, 0);
    transpose_cvt<<<(DI_ * 2 * DI_ + 255) / 256, 256, 0, stream>>>(W_bwd, WpT, DI_, 2 * DI_, 2 * DI_);
    transpose_cvt<<<(2 * DI_ * D_ + 255) / 256, 256, 0, stream>>>(W_out, WoutT, 2 * DI_, D_, 0);

    // 2. GEMM1: z = x @ W_in  [16384 x 2048] x [2048 x 256], fp32 A reg-staged.
    //    TBN=256 => x streamed from HBM exactly once (was 4x).
    gemm_bt<64, 256, 0, true><<<dim3(M_ / 64, 1), 256, 0, stream>>>(
        x, WinT, D_, DI_, z, nullptr, nullptr, nullptr, nullptr, nullptr);

    // 3. GEMM2 fused dirs: o = z @ [W_fwd|W_bwd]; delta=sigmoid, gate=o*z
    gemm_bt<128, 128, 1, false><<<dim3(M_ / 128, 1024 / 128), 256, 0, stream>>>(
        z, WpT, DI_, 1024, del_f, gat_f, del_b, gat_b, z, nullptr);

    // 4. chunked scans (dir in blockIdx.z), write concat [h_f|h_b]
    scan_agg<<<dim3(NC, B_, 2), DI_, 0, stream>>>(del_f, gat_f, del_b, gat_b, aggA, aggB);
    scan_mid<<<dim3(B_, 2), DI_, 0, stream>>>(aggA, aggB, Hin);
    scan_fix<<<dim3(NC, B_, 2), DI_, 0, stream>>>(del_f, gat_f, del_b, gat_b, Hin, hcat);

    // 5. GEMM3: y = hcat @ W_out + x  [16384 x 512] x [512 x 2048] -> ybuf bf16
    gemm_bt<128, 128, 2, false><<<dim3(M_ / 128, D_ / 128), 256, 0, stream>>>(
        hcat, WoutT, 2 * DI_, D_, ybuf, nullptr, nullptr, nullptr, nullptr, x);

    // 6. LayerNorm: ybuf -> fp32 out
    ln_kernel<<<M_, 256, 0, stream>>>(ybuf, gamma, beta, out);
}

// Round 4
// 436.810 us; speedup vs baseline: 1.0215x; 1.0215x over previous
//
#include <hip/hip_runtime.h>
#include <hip/hip_bf16.h>

using bf16 = __hip_bfloat16;
typedef float float4v __attribute__((ext_vector_type(4)));
typedef __bf16 bf16x8 __attribute__((ext_vector_type(8)));
typedef unsigned short ushort4v __attribute__((ext_vector_type(4)));
typedef unsigned short ushort8v __attribute__((ext_vector_type(8)));

#define B_  4
#define L_  4096
#define D_  2048
#define DI_ 256
#define M_  (B_*L_)       // 16384 rows
#define NC  64            // scan chunks per sequence
#define LC  (L_/NC)       // 64 steps per chunk

__device__ inline float bf2f(bf16 x) { return __bfloat162float(x); }
__device__ inline bf16  f2bf(float x) { return __float2bfloat16(x); }

__device__ inline void store4bf(bf16* p, float4v v) {
    ushort4v u;
#pragma unroll
    for (int i = 0; i < 4; i++) {
        bf16 h = f2bf(v[i]);
        u[i] = *(unsigned short*)&h;
    }
    *(ushort4v*)p = u;   // single 8B store
}

__device__ inline float4v load4bf(const bf16* p) {
    ushort4v u = *(const ushort4v*)p;
    float4v v;
#pragma unroll
    for (int i = 0; i < 4; i++) v[i] = __uint_as_float(((unsigned)u[i]) << 16);
    return v;
}

__device__ inline ushort8v cvt8(float4v a, float4v b) {
    ushort8v u;
#pragma unroll
    for (int i = 0; i < 4; i++) {
        bf16 h0 = f2bf(a[i]); u[i]     = *(unsigned short*)&h0;
        bf16 h1 = f2bf(b[i]); u[i + 4] = *(unsigned short*)&h1;
    }
    return u;
}

// async global->LDS, 16B per lane. LDS dest is wave-uniform base + lane*16.
__device__ __forceinline__ void gload_lds16(const bf16* g, bf16* l) {
    __builtin_amdgcn_global_load_lds((const __attribute__((address_space(1))) void*)(g),
                                     (__attribute__((address_space(3))) void*)(l),
                                     16, 0, 0);
}

template<int N> __device__ __forceinline__ void vmwait() {
    asm volatile("s_waitcnt vmcnt(%0)" :: "n"(N) : "memory");
}
template<int N> __device__ __forceinline__ void vmwait_lgkm0() {
    asm volatile("s_waitcnt vmcnt(%0) lgkmcnt(0)" :: "n"(N) : "memory");
}
__device__ __forceinline__ void bar() {
    asm volatile("" ::: "memory");
    __builtin_amdgcn_s_barrier();
    asm volatile("" ::: "memory");
}

// ---------------------------------------------------------------------------
// Transpose+convert: in fp32 [R,C] -> out bf16 [C+obase, R] rows (weights only)
// ---------------------------------------------------------------------------
__global__ void transpose_cvt(const float* __restrict__ in, bf16* __restrict__ out,
                              int R, int C, int obase) {
    int idx = blockIdx.x * 256 + threadIdx.x;
    if (idx < R * C) {
        int r = idx / C, c = idx - r * C;
        out[(size_t)(c + obase) * R + r] = f2bf(in[idx]);
    }
}

// ---------------------------------------------------------------------------
// MFMA GEMM: C[M,N] = A[M,K] x BT[N,K].  Counted-vmcnt pipeline.
//   bf16 path: depth-2 (2 LDS buffers), vmcnt(AP+BP) at top, stage t+2 after
//              compute.  AF32 path (A fp32): depth-3 (3 LDS buffers + 3-deep
//              A-register ping-pong, statically indexed), A global->reg->
//              cvt->LDS one tile ahead; derived waits (AI=2*AP):
//                top:    vmcnt(2*(AI+BP)) lgkmcnt(0)   [B(t) landed]
//                bottom: vmcnt(2*AI+3*BP)              [A(t+1) regs landed]
//              with exact tail drains.
// K-ROTATION: block starts its K loop at tile t0=(5*bm+3*bn)&(nt-1) and wraps
// -> concurrent blocks read DIFFERENT k-slices of shared panels (breaks L2
// same-line lockstep contention). Only changes fp32 accumulate order.
// LDS: linear [row][32k] with XOR slot-swizzle via pre-swizzled GLOBAL source
// (slot s of row r holds k-slot s ^ ((r>>1)&3)); ds_read slot quad^((l15>>1)&3).
// EPI: 0 = store bf16; 1 = delta/gate 4-way split (N=1024, aux=z);
//      2 = +fp32 residual (auxf = x), store bf16
// ---------------------------------------------------------------------------
#define BK 32

template<int TBM, int TBN, int EPI, bool AF32>
__global__ __launch_bounds__(256) void gemm_bt(const void* __restrict__ Av,
                                               const bf16* __restrict__ BT,
                                               int K, int N,
                                               bf16* __restrict__ o0, bf16* __restrict__ o1,
                                               bf16* __restrict__ o2, bf16* __restrict__ o3,
                                               const bf16* __restrict__ auxb,
                                               const float* __restrict__ auxf) {
    constexpr int MI  = TBM / 32, NI = TBN / 32, AP = TBM / 64, BP = TBN / 64;
    constexpr int AI  = 2 * AP;                     // A VMEM instrs/thread (fp32 path)
    constexpr int ASZ = TBM * 32, BSZ = TBN * 32;   // bf16 elems per buffer
    constexpr int ND  = AF32 ? 3 : 2;               // pipeline depth
    __shared__ __align__(16) bf16 As[ND * ASZ];
    __shared__ __align__(16) bf16 Bs[ND * BSZ];
    const int tid  = threadIdx.x;
    const int bm   = blockIdx.x, bn = blockIdx.y;
    const int lane = tid & 63, wave = tid >> 6;
    const int wm   = (wave >> 1) * (TBM / 2), wn = (wave & 1) * (TBN / 2);
    const int l15  = lane & 15, quad = lane >> 4;
    const int rsub  = lane >> 2;                      // row within a 16-row stage instr
    const int kslot = (lane & 3) ^ ((lane >> 3) & 3); // pre-swizzled global k-slot
    const int sq    = quad ^ ((l15 >> 1) & 3);        // swizzled read slot
    const int sr    = tid >> 2, scs = tid & 3;        // AF32 staging row / k-slot
    const int swslot = scs ^ ((sr >> 1) & 3);         // AF32 swizzled write slot

    float4v acc[MI][NI] = {};
    const float* Af = (const float*)Av;
    const bf16*  Ab = (const bf16*)Av;
    float4v fa0[AP][2], fa1[AP][2], fa2[AP][2];

    const int nt   = K / BK;
    const int mask = nt - 1;                          // nt is a power of 2
    const int t0   = (bm * 5 + bn * 3) & mask;
    auto T = [&](int i) { return ((i + t0) & mask) * BK; };

    auto stage_a = [&](int buf, int kk) {             // bf16 A via DMA (AP instrs)
#pragma unroll
        for (int p = 0; p < AP; p++) {
            int rbase = wave * (TBM / 4) + p * 16;
            gload_lds16(Ab + (size_t)(bm * TBM + rbase + rsub) * K + kk + kslot * 8,
                        As + buf * ASZ + rbase * 32 + lane * 8);
        }
    };
    auto stage_b = [&](int buf, int kk) {             // bf16 B via DMA (BP instrs)
#pragma unroll
        for (int p = 0; p < BP; p++) {
            int rbase = wave * (TBN / 4) + p * 16;
            gload_lds16(BT + (size_t)(bn * TBN + rbase + rsub) * K + kk + kslot * 8,
                        Bs + buf * BSZ + rbase * 32 + lane * 8);
        }
    };
    auto load_a_f32 = [&](float4v (&fa)[AP][2], int kk) {  // fp32 A -> regs (AI loads)
#pragma unroll
        for (int p = 0; p < AP; p++) {
            const float* src = Af + (size_t)(bm * TBM + p * 64 + sr) * K + kk + scs * 8;
            fa[p][0] = *(const float4v*)src;
            fa[p][1] = *(const float4v*)(src + 4);
        }
    };
    auto write_a_f32 = [&](float4v (&fa)[AP][2], int buf) {  // regs -> LDS (swizzled)
#pragma unroll
        for (int p = 0; p < AP; p++)
            *(ushort8v*)(As + buf * ASZ + (p * 64 + sr) * 32 + swslot * 8)
                = cvt8(fa[p][0], fa[p][1]);
    };
    auto compute = [&](int buf) {
        bf16x8 af[MI], bfr[NI];
#pragma unroll
        for (int mi = 0; mi < MI; mi++)
            af[mi] = *(const bf16x8*)(As + buf * ASZ + (wm + mi * 16 + l15) * 32 + sq * 8);
#pragma unroll
        for (int ni = 0; ni < NI; ni++)
            bfr[ni] = *(const bf16x8*)(Bs + buf * BSZ + (wn + ni * 16 + l15) * 32 + sq * 8);
        __builtin_amdgcn_s_setprio(1);
#pragma unroll
        for (int mi = 0; mi < MI; mi++)
#pragma unroll
            for (int ni = 0; ni < NI; ni++)
                acc[mi][ni] = __builtin_amdgcn_mfma_f32_16x16x32_bf16(
                    bfr[ni], af[mi], acc[mi][ni], 0, 0, 0);
        __builtin_amdgcn_s_setprio(0);
    };

    if constexpr (AF32) {
        // depth-3 prologue: A(0..2)->regs, B(0..2)->bufs
        load_a_f32(fa0, T(0)); stage_b(0, T(0));
        load_a_f32(fa1, T(1)); stage_b(1, T(1));
        load_a_f32(fa2, T(2)); stage_b(2, T(2));
        vmwait<2 * AI + 3 * BP>();        // A(0) landed (B0..B2, A1, A2 in flight)
        write_a_f32(fa0, 0);

        // body(t): compute buf, prefetch tile t+3, cvt+write A(t+1) into nbuf
        auto body = [&](int t, int bi, int nbuf,
                        float4v (&fcur)[AP][2], float4v (&fnext)[AP][2]) {
            int k = nt - 1 - t;               // tiles still in flight at top
            if (k >= 2)      vmwait_lgkm0<2 * (AI + BP)>();
            else if (k == 1) vmwait_lgkm0<AI + BP>();
            else             vmwait_lgkm0<0>();
            bar();
            compute(bi);
            bar();
            if (t + 3 < nt) { load_a_f32(fcur, T(t + 3)); stage_b(bi, T(t + 3)); }
            if (t + 1 < nt) {
                if (t + 3 < nt)      vmwait<2 * AI + 3 * BP>();
                else if (t + 2 < nt) vmwait<AI + 2 * BP>();
                else                 vmwait<BP>();
                write_a_f32(fnext, nbuf);
            }
        };
        int t = 0;
        for (; t + 3 <= nt; t += 3) {
            body(t,     0, 1, fa0, fa1);
            body(t + 1, 1, 2, fa1, fa2);
            body(t + 2, 2, 0, fa2, fa0);
        }
        if (t < nt)     body(t,     0, 1, fa0, fa1);
        if (t + 1 < nt) body(t + 1, 1, 2, fa1, fa2);
    } else {
        stage_a(0, T(0)); stage_b(0, T(0));
        stage_a(1, T(1)); stage_b(1, T(1));
        for (int t = 0; t < nt; t++) {
            if (t == nt - 1) vmwait<0>(); else vmwait<AP + BP>();
            bar();
            compute(t & 1);
            bar();
            if (t + 2 < nt) {
                stage_a(t & 1, T(t + 2));
                stage_b(t & 1, T(t + 2));
            }
        }
    }

    // Swapped layout: row(M) = l15-based, cols = quad*4 + reg (4 consecutive)
#pragma unroll
    for (int mi = 0; mi < MI; mi++) {
#pragma unroll
        for (int ni = 0; ni < NI; ni++) {
            int row = bm * TBM + wm + mi * 16 + l15;
            int col = bn * TBN + wn + ni * 16 + quad * 4;
            float4v v = acc[mi][ni];
            if (EPI == 0) {
                store4bf(o0 + (size_t)row * N + col, v);
            } else if (EPI == 1) {
                int sel = col >> 8, d = col & 255;
                bf16* dst = (sel == 0) ? o0 : (sel == 1) ? o1 : (sel == 2) ? o2 : o3;
                if (sel & 1) {   // gate = o * z
                    float4v z4 = load4bf(auxb + (size_t)row * DI_ + d);
#pragma unroll
                    for (int i = 0; i < 4; i++) v[i] *= z4[i];
                } else {         // delta = sigmoid(o)
#pragma unroll
                    for (int i = 0; i < 4; i++) v[i] = 1.f / (1.f + __expf(-v[i]));
                }
                store4bf(dst + (size_t)row * DI_ + d, v);
            } else {
                float4v r = *(const float4v*)(auxf + (size_t)row * N + col);
#pragma unroll
                for (int i = 0; i < 4; i++) v[i] += r[i];
                store4bf(o0 + (size_t)row * N + col, v);
            }
        }
    }
}

// ---------------------------------------------------------------------------
// Chunked linear-recurrence scan: h_t = delta_t * h_{t-1} + gate_t
// blockIdx.z = direction (0 fwd, 1 bwd/reversed)
// ---------------------------------------------------------------------------
__global__ __launch_bounds__(256) void scan_agg(const bf16* __restrict__ del_f,
                                                const bf16* __restrict__ gat_f,
                                                const bf16* __restrict__ del_b,
                                                const bf16* __restrict__ gat_b,
                                                float* __restrict__ aggA,
                                                float* __restrict__ aggB) {
    int c = blockIdx.x, b = blockIdx.y, dir = blockIdx.z, d = threadIdx.x;
    const bf16* delta = dir ? del_b : del_f;
    const bf16* gate  = dir ? gat_b : gat_f;
    float Ap = 1.f, h = 0.f;
    for (int i = 0; i < LC; i++) {
        int t = dir ? (L_ - 1 - (c * LC + i)) : (c * LC + i);
        size_t base = ((size_t)(b * L_ + t)) * DI_ + d;
        float dlt = bf2f(delta[base]);
        float g   = bf2f(gate[base]);
        Ap *= dlt;
        h = h * dlt + g;
    }
    size_t idx = (((size_t)dir * B_ + b) * NC + c) * DI_ + d;
    aggA[idx] = Ap;
    aggB[idx] = h;
}

__global__ void scan_mid(const float* __restrict__ aggA, const float* __restrict__ aggB,
                         float* __restrict__ Hin) {
    int b = blockIdx.x, dir = blockIdx.y, d = threadIdx.x;
    float h = 0.f;
    for (int c = 0; c < NC; c++) {
        size_t idx = (((size_t)dir * B_ + b) * NC + c) * DI_ + d;
        Hin[idx] = h;
        h = aggA[idx] * h + aggB[idx];
    }
}

__global__ __launch_bounds__(256) void scan_fix(const bf16* __restrict__ del_f,
                                                const bf16* __restrict__ gat_f,
                                                const bf16* __restrict__ del_b,
                                                const bf16* __restrict__ gat_b,
                                                const float* __restrict__ Hin,
                                                bf16* __restrict__ hcat) {
    int c = blockIdx.x, b = blockIdx.y, dir = blockIdx.z, d = threadIdx.x;
    const bf16* delta = dir ? del_b : del_f;
    const bf16* gate  = dir ? gat_b : gat_f;
    float h = Hin[(((size_t)dir * B_ + b) * NC + c) * DI_ + d];
    int colbase = dir * DI_;
    for (int i = 0; i < LC; i++) {
        int t = dir ? (L_ - 1 - (c * LC + i)) : (c * LC + i);
        size_t base = ((size_t)(b * L_ + t)) * DI_ + d;
        float dlt = bf2f(delta[base]);
        float g   = bf2f(gate[base]);
        h = h * dlt + g;
        hcat[((size_t)(b * L_ + t)) * (2 * DI_) + colbase + d] = f2bf(h);
    }
}

// ---------------------------------------------------------------------------
// LayerNorm over D=2048: reads bf16 ybuf, writes fp32 out. Fully vectorized.
// ---------------------------------------------------------------------------
__global__ __launch_bounds__(256) void ln_kernel(const bf16* __restrict__ y,
                                                 const float* __restrict__ gamma,
                                                 const float* __restrict__ beta,
                                                 float* __restrict__ outp) {
    __shared__ float ss[4], ssq[4];
    int row = blockIdx.x, tid = threadIdx.x;
    size_t base = (size_t)row * D_ + tid * 8;
    uint4 raw = *(const uint4*)(y + base);
    const unsigned short* u = (const unsigned short*)&raw;
    float v[8];
    float s = 0.f, sq = 0.f;
#pragma unroll
    for (int i = 0; i < 8; i++) {
        v[i] = __uint_as_float(((unsigned)u[i]) << 16);
        s += v[i];
        sq += v[i] * v[i];
    }
    for (int o = 32; o > 0; o >>= 1) { s += __shfl_down(s, o); sq += __shfl_down(sq, o); }
    if ((tid & 63) == 0) { ss[tid >> 6] = s; ssq[tid >> 6] = sq; }
    __syncthreads();
    float S  = ss[0] + ss[1] + ss[2] + ss[3];
    float SQ = ssq[0] + ssq[1] + ssq[2] + ssq[3];
    float mean = S * (1.f / D_);
    float var  = SQ * (1.f / D_) - mean * mean;
    float rstd = rsqrtf(var + 1e-5f);
    float4v g0 = *(const float4v*)(gamma + tid * 8);
    float4v g1 = *(const float4v*)(gamma + tid * 8 + 4);
    float4v b0 = *(const float4v*)(beta + tid * 8);
    float4v b1 = *(const float4v*)(beta + tid * 8 + 4);
    float4v r0, r1;
#pragma unroll
    for (int i = 0; i < 4; i++) {
        r0[i] = (v[i] - mean) * rstd * g0[i] + b0[i];
        r1[i] = (v[i + 4] - mean) * rstd * g1[i] + b1[i];
    }
    *(float4v*)(outp + base)     = r0;
    *(float4v*)(outp + base + 4) = r1;
}

// ---------------------------------------------------------------------------
extern "C" void kernel_launch(void* const* d_in, const int* in_sizes, int n_in,
                              void* d_out, int out_size, void* d_ws, size_t ws_size,
                              hipStream_t stream) {
    (void)in_sizes; (void)n_in; (void)out_size; (void)ws_size;
    const float* x     = (const float*)d_in[0];
    const float* W_in  = (const float*)d_in[1];
    const float* W_fwd = (const float*)d_in[2];
    const float* W_bwd = (const float*)d_in[3];
    const float* W_out = (const float*)d_in[4];
    const float* gamma = (const float*)d_in[5];
    const float* beta  = (const float*)d_in[6];
    float* out = (float*)d_out;

    char* ws = (char*)d_ws;
    size_t off = 0;
    auto alloc = [&](size_t bytes) -> char* {
        char* p = ws + off;
        off += (bytes + 255) & ~(size_t)255;
        return p;
    };
    bf16*  WinT   = (bf16*)alloc((size_t)DI_ * D_ * 2);           // [256, 2048]
    bf16*  WpT    = (bf16*)alloc((size_t)1024 * DI_ * 2);         // [1024, 256] fwd|bwd
    bf16*  WoutT  = (bf16*)alloc((size_t)D_ * 2 * DI_ * 2);       // [2048, 512]
    bf16*  z      = (bf16*)alloc((size_t)M_ * DI_ * 2);
    bf16*  del_f  = (bf16*)alloc((size_t)M_ * DI_ * 2);
    bf16*  gat_f  = (bf16*)alloc((size_t)M_ * DI_ * 2);
    bf16*  del_b  = (bf16*)alloc((size_t)M_ * DI_ * 2);
    bf16*  gat_b  = (bf16*)alloc((size_t)M_ * DI_ * 2);
    bf16*  hcat   = (bf16*)alloc((size_t)M_ * 2 * DI_ * 2);       // 16.8 MB
    bf16*  ybuf   = (bf16*)alloc((size_t)M_ * D_ * 2);            // 67 MB
    float* aggA   = (float*)alloc((size_t)2 * B_ * NC * DI_ * 4);
    float* aggB   = (float*)alloc((size_t)2 * B_ * NC * DI_ * 4);
    float* Hin    = (float*)alloc((size_t)2 * B_ * NC * DI_ * 4);

    // 1. weight transposes (fp32 -> bf16 [N,K])
    transpose_cvt<<<(D_ * DI_ + 255) / 256, 256, 0, stream>>>(W_in, WinT, D_, DI_, 0);
    transpose_cvt<<<(DI_ * 2 * DI_ + 255) / 256, 256, 0, stream>>>(W_fwd, WpT, DI_, 2 * DI_, 0);
    transpose_cvt<<<(DI_ * 2 * DI_ + 255) / 256, 256, 0, stream>>>(W_bwd, WpT, DI_, 2 * DI_, 2 * DI_);
    transpose_cvt<<<(2 * DI_ * D_ + 255) / 256, 256, 0, stream>>>(W_out, WoutT, 2 * DI_, D_, 0);

    // 2. GEMM1: z = x @ W_in  [16384 x 2048] x [2048 x 256], fp32 A reg-staged.
    //    <64,128> grid (256,2) -> 2 blocks/CU; depth-3 pipeline; K-rotation.
    gemm_bt<64, 128, 0, true><<<dim3(M_ / 64, 2), 256, 0, stream>>>(
        x, WinT, D_, DI_, z, nullptr, nullptr, nullptr, nullptr, nullptr);

    // 3. GEMM2 fused dirs: o = z @ [W_fwd|W_bwd]; delta=sigmoid, gate=o*z
    gemm_bt<128, 128, 1, false><<<dim3(M_ / 128, 1024 / 128), 256, 0, stream>>>(
        z, WpT, DI_, 1024, del_f, gat_f, del_b, gat_b, z, nullptr);

    // 4. chunked scans (dir in blockIdx.z), write concat [h_f|h_b]
    scan_agg<<<dim3(NC, B_, 2), DI_, 0, stream>>>(del_f, gat_f, del_b, gat_b, aggA, aggB);
    scan_mid<<<dim3(B_, 2), DI_, 0, stream>>>(aggA, aggB, Hin);
    scan_fix<<<dim3(NC, B_, 2), DI_, 0, stream>>>(del_f, gat_f, del_b, gat_b, Hin, hcat);

    // 5. GEMM3: y = hcat @ W_out + x  [16384 x 512] x [512 x 2048] -> ybuf bf16
    gemm_bt<128, 128, 2, false><<<dim3(M_ / 128, D_ / 128), 256, 0, stream>>>(
        hcat, WoutT, 2 * DI_, D_, ybuf, nullptr, nullptr, nullptr, nullptr, x);

    // 6. LayerNorm: ybuf -> fp32 out
    ln_kernel<<<M_, 256, 0, stream>>>(ybuf, gamma, beta, out);
}

// Round 5
// 420.420 us; speedup vs baseline: 1.0613x; 1.0390x over previous
//
#include <hip/hip_runtime.h>
#include <hip/hip_bf16.h>

using bf16 = __hip_bfloat16;
typedef float float4v __attribute__((ext_vector_type(4)));
typedef __bf16 bf16x8 __attribute__((ext_vector_type(8)));
typedef unsigned short ushort4v __attribute__((ext_vector_type(4)));
typedef unsigned short ushort8v __attribute__((ext_vector_type(8)));

#define B_  4
#define L_  4096
#define D_  2048
#define DI_ 256
#define M_  (B_*L_)       // 16384 rows
#define NC  64            // scan chunks per sequence
#define LC  (L_/NC)       // 64 steps per chunk

__device__ inline float bf2f(bf16 x) { return __bfloat162float(x); }
__device__ inline bf16  f2bf(float x) { return __float2bfloat16(x); }

__device__ inline void store4bf(bf16* p, float4v v) {
    ushort4v u;
#pragma unroll
    for (int i = 0; i < 4; i++) {
        bf16 h = f2bf(v[i]);
        u[i] = *(unsigned short*)&h;
    }
    *(ushort4v*)p = u;   // single 8B store
}

__device__ inline float4v load4bf(const bf16* p) {
    ushort4v u = *(const ushort4v*)p;
    float4v v;
#pragma unroll
    for (int i = 0; i < 4; i++) v[i] = __uint_as_float(((unsigned)u[i]) << 16);
    return v;
}

__device__ inline ushort8v cvt8(float4v a, float4v b) {
    ushort8v u;
#pragma unroll
    for (int i = 0; i < 4; i++) {
        bf16 h0 = f2bf(a[i]); u[i]     = *(unsigned short*)&h0;
        bf16 h1 = f2bf(b[i]); u[i + 4] = *(unsigned short*)&h1;
    }
    return u;
}

// async global->LDS, 16B per lane. LDS dest is wave-uniform base + lane*16.
__device__ __forceinline__ void gload_lds16(const bf16* g, bf16* l) {
    __builtin_amdgcn_global_load_lds((const __attribute__((address_space(1))) void*)(g),
                                     (__attribute__((address_space(3))) void*)(l),
                                     16, 0, 0);
}

template<int N> __device__ __forceinline__ void vmwait() {
    asm volatile("s_waitcnt vmcnt(%0)" :: "n"(N) : "memory");
}
template<int N> __device__ __forceinline__ void vmwait_lgkm0() {
    asm volatile("s_waitcnt vmcnt(%0) lgkmcnt(0)" :: "n"(N) : "memory");
}
__device__ __forceinline__ void bar() {
    asm volatile("" ::: "memory");
    __builtin_amdgcn_s_barrier();
    asm volatile("" ::: "memory");
}

// ---------------------------------------------------------------------------
// Transpose+convert: in fp32 [R,C] -> out bf16 [C+obase, R] rows (weights only)
// ---------------------------------------------------------------------------
__global__ void transpose_cvt(const float* __restrict__ in, bf16* __restrict__ out,
                              int R, int C, int obase) {
    int idx = blockIdx.x * 256 + threadIdx.x;
    if (idx < R * C) {
        int r = idx / C, c = idx - r * C;
        out[(size_t)(c + obase) * R + r] = f2bf(in[idx]);
    }
}

// ---------------------------------------------------------------------------
// MFMA GEMM: C[M,N] = A[M,K] x BT[N,K].  Counted-vmcnt pipeline, K-step BKT.
//   bf16 path (BKT=64): depth-2, per iter {vmwait(API+BPI); bar; 2x(16 ds_read
//     + 16 MFMA); bar; stage t+2} -> 2x work per phase vs BKT=32 amortizes
//     barrier/latency/addressing fixed cost. LDS 64KB -> 2 blocks/CU.
//   AF32 path (BKT=32, GEMM1): depth-3 + 3-deep A-register ping-pong with
//     K-rotation (unchanged from prior round; verified).
// LDS swizzle (both): slot s (16B) of row r holds global k-slot s ^ swz(r),
// realized by pre-swizzling the GLOBAL source (gload_lds writes linearly);
// ds_read applies the same involution. swz(r) = (r>>1)&3 for BKT=32 (row
// stride 16 words, row parity flips bank-half), r&7 for BKT=64 (row stride
// 32 words). Both give 2 lanes per 4-bank group per 16-lane cycle = free.
// EPI: 0 = store bf16; 1 = delta/gate 4-way split (N=1024, aux=z);
//      2 = +fp32 residual (auxf = x), store bf16
// ---------------------------------------------------------------------------

template<int TBM, int TBN, int BKT, int EPI, bool AF32>
__global__ __launch_bounds__(256) void gemm_bt(const void* __restrict__ Av,
                                               const bf16* __restrict__ BT,
                                               int K, int N,
                                               bf16* __restrict__ o0, bf16* __restrict__ o1,
                                               bf16* __restrict__ o2, bf16* __restrict__ o3,
                                               const bf16* __restrict__ auxb,
                                               const float* __restrict__ auxf) {
    constexpr int MI  = TBM / 32, NI = TBN / 32;
    constexpr int SLOTS = BKT / 8;                  // 16B slots per row
    constexpr int RPI   = 64 / SLOTS;               // rows per stage instr
    constexpr int API   = TBM * SLOTS / 256;        // A stage instrs per wave
    constexpr int BPI   = TBN * SLOTS / 256;        // B stage instrs per wave
    constexpr int AP  = TBM / 64;                   // AF32 reg-tile rows/64
    constexpr int AI  = 2 * AP;                     // A VMEM instrs (fp32 path)
    constexpr int ASZ = TBM * BKT, BSZ = TBN * BKT; // bf16 elems per buffer
    constexpr int ND  = AF32 ? 3 : 2;               // pipeline depth
    __shared__ __align__(16) bf16 As[ND * ASZ];
    __shared__ __align__(16) bf16 Bs[ND * BSZ];
    const int tid  = threadIdx.x;
    const int bm   = blockIdx.x, bn = blockIdx.y;
    const int lane = tid & 63, wave = tid >> 6;
    const int wm   = (wave >> 1) * (TBM / 2), wn = (wave & 1) * (TBN / 2);
    const int l15  = lane & 15, quad = lane >> 4;
    const int srow  = lane / SLOTS;                   // row within a stage instr
    const int sslot = lane % SLOTS;                   // lds slot this lane fills
    const int kslot = sslot ^ ((BKT == 32) ? ((srow >> 1) & 3) : (srow & 7));
    const int sr    = tid >> 2, scs = tid & 3;        // AF32 staging row / k-slot
    const int swslot = scs ^ ((sr >> 1) & 3);         // AF32 swizzled write slot

    float4v acc[MI][NI] = {};
    const float* Af = (const float*)Av;
    const bf16*  Ab = (const bf16*)Av;
    float4v fa0[AP][2], fa1[AP][2], fa2[AP][2];

    const int nt   = K / BKT;
    const int mask = nt - 1;                          // nt is a power of 2
    const int t0   = AF32 ? ((bm * 5 + bn * 3) & mask) : 0;  // K-rotation (AF32 only)
    auto T = [&](int i) { return ((i + t0) & mask) * BKT; };

    auto stage_a = [&](int buf, int kk) {             // bf16 A via DMA (API instrs)
#pragma unroll
        for (int p = 0; p < API; p++) {
            int rbase = wave * (TBM / 4) + p * RPI;
            gload_lds16(Ab + (size_t)(bm * TBM + rbase + srow) * K + kk + kslot * 8,
                        As + buf * ASZ + rbase * BKT + lane * 8);
        }
    };
    auto stage_b = [&](int buf, int kk) {             // bf16 B via DMA (BPI instrs)
#pragma unroll
        for (int p = 0; p < BPI; p++) {
            int rbase = wave * (TBN / 4) + p * RPI;
            gload_lds16(BT + (size_t)(bn * TBN + rbase + srow) * K + kk + kslot * 8,
                        Bs + buf * BSZ + rbase * BKT + lane * 8);
        }
    };
    auto load_a_f32 = [&](float4v (&fa)[AP][2], int kk) {  // fp32 A -> regs (AI loads)
#pragma unroll
        for (int p = 0; p < AP; p++) {
            const float* src = Af + (size_t)(bm * TBM + p * 64 + sr) * K + kk + scs * 8;
            fa[p][0] = *(const float4v*)src;
            fa[p][1] = *(const float4v*)(src + 4);
        }
    };
    auto write_a_f32 = [&](float4v (&fa)[AP][2], int buf) {  // regs -> LDS (swizzled)
#pragma unroll
        for (int p = 0; p < AP; p++)
            *(ushort8v*)(As + buf * ASZ + (p * 64 + sr) * BKT + swslot * 8)
                = cvt8(fa[p][0], fa[p][1]);
    };
    auto compute = [&](int buf) {
#pragma unroll
        for (int h = 0; h < BKT / 32; h++) {
            const int s = (BKT == 32) ? (quad ^ ((l15 >> 1) & 3))
                                      : ((quad + 4 * h) ^ (l15 & 7));
            bf16x8 af[MI], bfr[NI];
#pragma unroll
            for (int mi = 0; mi < MI; mi++)
                af[mi] = *(const bf16x8*)(As + buf * ASZ + (wm + mi * 16 + l15) * BKT + s * 8);
#pragma unroll
            for (int ni = 0; ni < NI; ni++)
                bfr[ni] = *(const bf16x8*)(Bs + buf * BSZ + (wn + ni * 16 + l15) * BKT + s * 8);
            __builtin_amdgcn_s_setprio(1);
#pragma unroll
            for (int mi = 0; mi < MI; mi++)
#pragma unroll
                for (int ni = 0; ni < NI; ni++)
                    acc[mi][ni] = __builtin_amdgcn_mfma_f32_16x16x32_bf16(
                        bfr[ni], af[mi], acc[mi][ni], 0, 0, 0);
            __builtin_amdgcn_s_setprio(0);
        }
    };

    if constexpr (AF32) {
        // depth-3 prologue: A(0..2)->regs, B(0..2)->bufs
        load_a_f32(fa0, T(0)); stage_b(0, T(0));
        load_a_f32(fa1, T(1)); stage_b(1, T(1));
        load_a_f32(fa2, T(2)); stage_b(2, T(2));
        vmwait<2 * AI + 3 * BPI>();       // A(0) landed (B0..B2, A1, A2 in flight)
        write_a_f32(fa0, 0);

        // body(t): compute buf, prefetch tile t+3, cvt+write A(t+1) into nbuf
        auto body = [&](int t, int bi, int nbuf,
                        float4v (&fcur)[AP][2], float4v (&fnext)[AP][2]) {
            int k = nt - 1 - t;               // tiles still in flight at top
            if (k >= 2)      vmwait_lgkm0<2 * (AI + BPI)>();
            else if (k == 1) vmwait_lgkm0<AI + BPI>();
            else             vmwait_lgkm0<0>();
            bar();
            compute(bi);
            bar();
            if (t + 3 < nt) { load_a_f32(fcur, T(t + 3)); stage_b(bi, T(t + 3)); }
            if (t + 1 < nt) {
                if (t + 3 < nt)      vmwait<2 * AI + 3 * BPI>();
                else if (t + 2 < nt) vmwait<AI + 2 * BPI>();
                else                 vmwait<BPI>();
                write_a_f32(fnext, nbuf);
            }
        };
        int t = 0;
        for (; t + 3 <= nt; t += 3) {
            body(t,     0, 1, fa0, fa1);
            body(t + 1, 1, 2, fa1, fa2);
            body(t + 2, 2, 0, fa2, fa0);
        }
        if (t < nt)     body(t,     0, 1, fa0, fa1);
        if (t + 1 < nt) body(t + 1, 1, 2, fa1, fa2);
    } else {
        stage_a(0, 0);     stage_b(0, 0);
        stage_a(1, BKT);   stage_b(1, BKT);
        for (int t = 0; t < nt; t++) {
            if (t == nt - 1) vmwait<0>(); else vmwait<API + BPI>();
            bar();
            compute(t & 1);
            bar();
            if (t + 2 < nt) {
                stage_a(t & 1, (t + 2) * BKT);
                stage_b(t & 1, (t + 2) * BKT);
            }
        }
    }

    // Swapped layout: row(M) = l15-based, cols = quad*4 + reg (4 consecutive)
#pragma unroll
    for (int mi = 0; mi < MI; mi++) {
#pragma unroll
        for (int ni = 0; ni < NI; ni++) {
            int row = bm * TBM + wm + mi * 16 + l15;
            int col = bn * TBN + wn + ni * 16 + quad * 4;
            float4v v = acc[mi][ni];
            if (EPI == 0) {
                store4bf(o0 + (size_t)row * N + col, v);
            } else if (EPI == 1) {
                int sel = col >> 8, d = col & 255;
                bf16* dst = (sel == 0) ? o0 : (sel == 1) ? o1 : (sel == 2) ? o2 : o3;
                if (sel & 1) {   // gate = o * z
                    float4v z4 = load4bf(auxb + (size_t)row * DI_ + d);
#pragma unroll
                    for (int i = 0; i < 4; i++) v[i] *= z4[i];
                } else {         // delta = sigmoid(o)
#pragma unroll
                    for (int i = 0; i < 4; i++) v[i] = 1.f / (1.f + __expf(-v[i]));
                }
                store4bf(dst + (size_t)row * DI_ + d, v);
            } else {
                float4v r = *(const float4v*)(auxf + (size_t)row * N + col);
#pragma unroll
                for (int i = 0; i < 4; i++) v[i] += r[i];
                store4bf(o0 + (size_t)row * N + col, v);
            }
        }
    }
}

// ---------------------------------------------------------------------------
// Chunked linear-recurrence scan: h_t = delta_t * h_{t-1} + gate_t
// blockIdx.z = direction (0 fwd, 1 bwd/reversed)
// ---------------------------------------------------------------------------
__global__ __launch_bounds__(256) void scan_agg(const bf16* __restrict__ del_f,
                                                const bf16* __restrict__ gat_f,
                                                const bf16* __restrict__ del_b,
                                                const bf16* __restrict__ gat_b,
                                                float* __restrict__ aggA,
                                                float* __restrict__ aggB) {
    int c = blockIdx.x, b = blockIdx.y, dir = blockIdx.z, d = threadIdx.x;
    const bf16* delta = dir ? del_b : del_f;
    const bf16* gate  = dir ? gat_b : gat_f;
    float Ap = 1.f, h = 0.f;
    for (int i = 0; i < LC; i++) {
        int t = dir ? (L_ - 1 - (c * LC + i)) : (c * LC + i);
        size_t base = ((size_t)(b * L_ + t)) * DI_ + d;
        float dlt = bf2f(delta[base]);
        float g   = bf2f(gate[base]);
        Ap *= dlt;
        h = h * dlt + g;
    }
    size_t idx = (((size_t)dir * B_ + b) * NC + c) * DI_ + d;
    aggA[idx] = Ap;
    aggB[idx] = h;
}

__global__ void scan_mid(const float* __restrict__ aggA, const float* __restrict__ aggB,
                         float* __restrict__ Hin) {
    int b = blockIdx.x, dir = blockIdx.y, d = threadIdx.x;
    float h = 0.f;
    for (int c = 0; c < NC; c++) {
        size_t idx = (((size_t)dir * B_ + b) * NC + c) * DI_ + d;
        Hin[idx] = h;
        h = aggA[idx] * h + aggB[idx];
    }
}

__global__ __launch_bounds__(256) void scan_fix(const bf16* __restrict__ del_f,
                                                const bf16* __restrict__ gat_f,
                                                const bf16* __restrict__ del_b,
                                                const bf16* __restrict__ gat_b,
                                                const float* __restrict__ Hin,
                                                bf16* __restrict__ hcat) {
    int c = blockIdx.x, b = blockIdx.y, dir = blockIdx.z, d = threadIdx.x;
    const bf16* delta = dir ? del_b : del_f;
    const bf16* gate  = dir ? gat_b : gat_f;
    float h = Hin[(((size_t)dir * B_ + b) * NC + c) * DI_ + d];
    int colbase = dir * DI_;
    for (int i = 0; i < LC; i++) {
        int t = dir ? (L_ - 1 - (c * LC + i)) : (c * LC + i);
        size_t base = ((size_t)(b * L_ + t)) * DI_ + d;
        float dlt = bf2f(delta[base]);
        float g   = bf2f(gate[base]);
        h = h * dlt + g;
        hcat[((size_t)(b * L_ + t)) * (2 * DI_) + colbase + d] = f2bf(h);
    }
}

// ---------------------------------------------------------------------------
// LayerNorm over D=2048: reads bf16 ybuf, writes fp32 out. Fully vectorized.
// ---------------------------------------------------------------------------
__global__ __launch_bounds__(256) void ln_kernel(const bf16* __restrict__ y,
                                                 const float* __restrict__ gamma,
                                                 const float* __restrict__ beta,
                                                 float* __restrict__ outp) {
    __shared__ float ss[4], ssq[4];
    int row = blockIdx.x, tid = threadIdx.x;
    size_t base = (size_t)row * D_ + tid * 8;
    uint4 raw = *(const uint4*)(y + base);
    const unsigned short* u = (const unsigned short*)&raw;
    float v[8];
    float s = 0.f, sq = 0.f;
#pragma unroll
    for (int i = 0; i < 8; i++) {
        v[i] = __uint_as_float(((unsigned)u[i]) << 16);
        s += v[i];
        sq += v[i] * v[i];
    }
    for (int o = 32; o > 0; o >>= 1) { s += __shfl_down(s, o); sq += __shfl_down(sq, o); }
    if ((tid & 63) == 0) { ss[tid >> 6] = s; ssq[tid >> 6] = sq; }
    __syncthreads();
    float S  = ss[0] + ss[1] + ss[2] + ss[3];
    float SQ = ssq[0] + ssq[1] + ssq[2] + ssq[3];
    float mean = S * (1.f / D_);
    float var  = SQ * (1.f / D_) - mean * mean;
    float rstd = rsqrtf(var + 1e-5f);
    float4v g0 = *(const float4v*)(gamma + tid * 8);
    float4v g1 = *(const float4v*)(gamma + tid * 8 + 4);
    float4v b0 = *(const float4v*)(beta + tid * 8);
    float4v b1 = *(const float4v*)(beta + tid * 8 + 4);
    float4v r0, r1;
#pragma unroll
    for (int i = 0; i < 4; i++) {
        r0[i] = (v[i] - mean) * rstd * g0[i] + b0[i];
        r1[i] = (v[i + 4] - mean) * rstd * g1[i] + b1[i];
    }
    *(float4v*)(outp + base)     = r0;
    *(float4v*)(outp + base + 4) = r1;
}

// ---------------------------------------------------------------------------
extern "C" void kernel_launch(void* const* d_in, const int* in_sizes, int n_in,
                              void* d_out, int out_size, void* d_ws, size_t ws_size,
                              hipStream_t stream) {
    (void)in_sizes; (void)n_in; (void)out_size; (void)ws_size;
    const float* x     = (const float*)d_in[0];
    const float* W_in  = (const float*)d_in[1];
    const float* W_fwd = (const float*)d_in[2];
    const float* W_bwd = (const float*)d_in[3];
    const float* W_out = (const float*)d_in[4];
    const float* gamma = (const float*)d_in[5];
    const float* beta  = (const float*)d_in[6];
    float* out = (float*)d_out;

    char* ws = (char*)d_ws;
    size_t off = 0;
    auto alloc = [&](size_t bytes) -> char* {
        char* p = ws + off;
        off += (bytes + 255) & ~(size_t)255;
        return p;
    };
    bf16*  WinT   = (bf16*)alloc((size_t)DI_ * D_ * 2);           // [256, 2048]
    bf16*  WpT    = (bf16*)alloc((size_t)1024 * DI_ * 2);         // [1024, 256] fwd|bwd
    bf16*  WoutT  = (bf16*)alloc((size_t)D_ * 2 * DI_ * 2);       // [2048, 512]
    bf16*  z      = (bf16*)alloc((size_t)M_ * DI_ * 2);
    bf16*  del_f  = (bf16*)alloc((size_t)M_ * DI_ * 2);
    bf16*  gat_f  = (bf16*)alloc((size_t)M_ * DI_ * 2);
    bf16*  del_b  = (bf16*)alloc((size_t)M_ * DI_ * 2);
    bf16*  gat_b  = (bf16*)alloc((size_t)M_ * DI_ * 2);
    bf16*  hcat   = (bf16*)alloc((size_t)M_ * 2 * DI_ * 2);       // 16.8 MB
    bf16*  ybuf   = (bf16*)alloc((size_t)M_ * D_ * 2);            // 67 MB
    float* aggA   = (float*)alloc((size_t)2 * B_ * NC * DI_ * 4);
    float* aggB   = (float*)alloc((size_t)2 * B_ * NC * DI_ * 4);
    float* Hin    = (float*)alloc((size_t)2 * B_ * NC * DI_ * 4);

    // 1. weight transposes (fp32 -> bf16 [N,K])
    transpose_cvt<<<(D_ * DI_ + 255) / 256, 256, 0, stream>>>(W_in, WinT, D_, DI_, 0);
    transpose_cvt<<<(DI_ * 2 * DI_ + 255) / 256, 256, 0, stream>>>(W_fwd, WpT, DI_, 2 * DI_, 0);
    transpose_cvt<<<(DI_ * 2 * DI_ + 255) / 256, 256, 0, stream>>>(W_bwd, WpT, DI_, 2 * DI_, 2 * DI_);
    transpose_cvt<<<(2 * DI_ * D_ + 255) / 256, 256, 0, stream>>>(W_out, WoutT, 2 * DI_, D_, 0);

    // 2. GEMM1: z = x @ W_in  [16384 x 2048] x [2048 x 256], fp32 A reg-staged.
    //    <64,128> grid (256,2) -> 2 blocks/CU; depth-3 pipeline; K-rotation.
    gemm_bt<64, 128, 32, 0, true><<<dim3(M_ / 64, 2), 256, 0, stream>>>(
        x, WinT, D_, DI_, z, nullptr, nullptr, nullptr, nullptr, nullptr);

    // 3. GEMM2 fused dirs: o = z @ [W_fwd|W_bwd]; delta=sigmoid, gate=o*z. BK=64.
    gemm_bt<128, 128, 64, 1, false><<<dim3(M_ / 128, 1024 / 128), 256, 0, stream>>>(
        z, WpT, DI_, 1024, del_f, gat_f, del_b, gat_b, z, nullptr);

    // 4. chunked scans (dir in blockIdx.z), write concat [h_f|h_b]
    scan_agg<<<dim3(NC, B_, 2), DI_, 0, stream>>>(del_f, gat_f, del_b, gat_b, aggA, aggB);
    scan_mid<<<dim3(B_, 2), DI_, 0, stream>>>(aggA, aggB, Hin);
    scan_fix<<<dim3(NC, B_, 2), DI_, 0, stream>>>(del_f, gat_f, del_b, gat_b, Hin, hcat);

    // 5. GEMM3: y = hcat @ W_out + x  [16384 x 512] x [512 x 2048] -> ybuf bf16. BK=64.
    gemm_bt<128, 128, 64, 2, false><<<dim3(M_ / 128, D_ / 128), 256, 0, stream>>>(
        hcat, WoutT, 2 * DI_, D_, ybuf, nullptr, nullptr, nullptr, nullptr, x);

    // 6. LayerNorm: ybuf -> fp32 out
    ln_kernel<<<M_, 256, 0, stream>>>(ybuf, gamma, beta, out);
}

// Round 6
// 415.153 us; speedup vs baseline: 1.0748x; 1.0127x over previous
//
#include <hip/hip_runtime.h>
#include <hip/hip_bf16.h>

using bf16 = __hip_bfloat16;
typedef float float4v __attribute__((ext_vector_type(4)));
typedef __bf16 bf16x8 __attribute__((ext_vector_type(8)));
typedef unsigned short ushort4v __attribute__((ext_vector_type(4)));
typedef unsigned short ushort8v __attribute__((ext_vector_type(8)));

#define B_  4
#define L_  4096
#define D_  2048
#define DI_ 256
#define M_  (B_*L_)       // 16384 rows
#define NC  64            // scan chunks per sequence
#define LC  (L_/NC)       // 64 steps per chunk

__device__ inline float bf2f(bf16 x) { return __bfloat162float(x); }
__device__ inline bf16  f2bf(float x) { return __float2bfloat16(x); }

__device__ inline void store4bf(bf16* p, float4v v) {
    ushort4v u;
#pragma unroll
    for (int i = 0; i < 4; i++) {
        bf16 h = f2bf(v[i]);
        u[i] = *(unsigned short*)&h;
    }
    *(ushort4v*)p = u;   // single 8B store
}

__device__ inline float4v load4bf(const bf16* p) {
    ushort4v u = *(const ushort4v*)p;
    float4v v;
#pragma unroll
    for (int i = 0; i < 4; i++) v[i] = __uint_as_float(((unsigned)u[i]) << 16);
    return v;
}

__device__ inline ushort8v cvt8(float4v a, float4v b) {
    ushort8v u;
#pragma unroll
    for (int i = 0; i < 4; i++) {
        bf16 h0 = f2bf(a[i]); u[i]     = *(unsigned short*)&h0;
        bf16 h1 = f2bf(b[i]); u[i + 4] = *(unsigned short*)&h1;
    }
    return u;
}

// async global->LDS, 16B per lane. LDS dest is wave-uniform base + lane*16.
__device__ __forceinline__ void gload_lds16(const bf16* g, bf16* l) {
    __builtin_amdgcn_global_load_lds((const __attribute__((address_space(1))) void*)(g),
                                     (__attribute__((address_space(3))) void*)(l),
                                     16, 0, 0);
}

template<int N> __device__ __forceinline__ void vmwait() {
    asm volatile("s_waitcnt vmcnt(%0)" :: "n"(N) : "memory");
}
template<int N> __device__ __forceinline__ void vmwait_lgkm0() {
    asm volatile("s_waitcnt vmcnt(%0) lgkmcnt(0)" :: "n"(N) : "memory");
}
__device__ __forceinline__ void bar() {
    asm volatile("" ::: "memory");
    __builtin_amdgcn_s_barrier();
    asm volatile("" ::: "memory");
}

// ---------------------------------------------------------------------------
// Fused weight transpose+convert: all 4 weights in ONE launch.
// fp32 [R,C] -> bf16 [C(+obase), R]
// ---------------------------------------------------------------------------
__global__ __launch_bounds__(256) void transpose_all(const float* __restrict__ W_in,
                                                     const float* __restrict__ W_fwd,
                                                     const float* __restrict__ W_bwd,
                                                     const float* __restrict__ W_out,
                                                     bf16* __restrict__ WinT,
                                                     bf16* __restrict__ WpT,
                                                     bf16* __restrict__ WoutT) {
    constexpr int S0 = D_ * DI_;          // W_in  [2048 x 256]
    constexpr int S1 = DI_ * 2 * DI_;     // W_fwd [256 x 512]
    constexpr int S2 = S1;                // W_bwd
    constexpr int S3 = 2 * DI_ * D_;      // W_out [512 x 2048]
    int idx = blockIdx.x * 256 + threadIdx.x;
    if (idx < S0) {
        int r = idx / DI_, c = idx - r * DI_;
        WinT[(size_t)c * D_ + r] = f2bf(W_in[idx]);
    } else if (idx < S0 + S1) {
        int j = idx - S0;
        int r = j / (2 * DI_), c = j - r * (2 * DI_);
        WpT[(size_t)c * DI_ + r] = f2bf(W_fwd[j]);
    } else if (idx < S0 + S1 + S2) {
        int j = idx - S0 - S1;
        int r = j / (2 * DI_), c = j - r * (2 * DI_);
        WpT[(size_t)(c + 2 * DI_) * DI_ + r] = f2bf(W_bwd[j]);
    } else if (idx < S0 + S1 + S2 + S3) {
        int j = idx - S0 - S1 - S2;
        int r = j / D_, c = j - r * D_;
        WoutT[(size_t)c * (2 * DI_) + r] = f2bf(W_out[j]);
    }
}

// ---------------------------------------------------------------------------
// MFMA GEMM: C[M,N] = A[M,K] x BT[N,K].
//   bf16 path (BKT=32, depth-3 ring, ONE barrier/iter): per iter
//     { vmwait(4); bar; ds_read frags; issue stage(t+2)->buf (t+2)%3
//       INSIDE compute; 16 MFMA }  -- stages overlap compute; no bottom
//     barrier needed: every ds_read is consumed by an MFMA before the wave
//     reaches the next top barrier, and stage targets a buffer 2 ahead in
//     the 3-ring, so no wave can write LDS another wave still reads.
//     LDS 48KB -> up to 3 blocks/CU.
//   AF32 path (BKT=32, GEMM1): depth-3 + 3-deep A-register ping-pong with
//     K-rotation, 2 barriers/iter (unchanged, verified).
// LDS swizzle (both): slot s (16B) of row r holds global k-slot s ^ swz(r),
// realized by pre-swizzling the GLOBAL source (gload_lds writes linearly);
// ds_read applies the same involution. swz(r) = (r>>1)&3 for BKT=32, r&7
// for BKT=64.
// EPI: 0 = store bf16; 1 = delta/gate 4-way split (N=1024, aux=z);
//      2 = +fp32 residual (auxf = x), store bf16
// ---------------------------------------------------------------------------

template<int TBM, int TBN, int BKT, int EPI, bool AF32>
__global__ __launch_bounds__(256) void gemm_bt(const void* __restrict__ Av,
                                               const bf16* __restrict__ BT,
                                               int K, int N,
                                               bf16* __restrict__ o0, bf16* __restrict__ o1,
                                               bf16* __restrict__ o2, bf16* __restrict__ o3,
                                               const bf16* __restrict__ auxb,
                                               const float* __restrict__ auxf) {
    constexpr int MI  = TBM / 32, NI = TBN / 32;
    constexpr int SLOTS = BKT / 8;                  // 16B slots per row
    constexpr int RPI   = 64 / SLOTS;               // rows per stage instr
    constexpr int API   = TBM * SLOTS / 256;        // A stage instrs per wave
    constexpr int BPI   = TBN * SLOTS / 256;        // B stage instrs per wave
    constexpr int AP  = TBM / 64;                   // AF32 reg-tile rows/64
    constexpr int AI  = 2 * AP;                     // A VMEM instrs (fp32 path)
    constexpr int ASZ = TBM * BKT, BSZ = TBN * BKT; // bf16 elems per buffer
    __shared__ __align__(16) bf16 As[3 * ASZ];
    __shared__ __align__(16) bf16 Bs[3 * BSZ];
    const int tid  = threadIdx.x;
    const int bm   = blockIdx.x, bn = blockIdx.y;
    const int lane = tid & 63, wave = tid >> 6;
    const int wm   = (wave >> 1) * (TBM / 2), wn = (wave & 1) * (TBN / 2);
    const int l15  = lane & 15, quad = lane >> 4;
    const int srow  = lane / SLOTS;                   // row within a stage instr
    const int sslot = lane % SLOTS;                   // lds slot this lane fills
    const int kslot = sslot ^ ((BKT == 32) ? ((srow >> 1) & 3) : (srow & 7));
    const int sr    = tid >> 2, scs = tid & 3;        // AF32 staging row / k-slot
    const int swslot = scs ^ ((sr >> 1) & 3);         // AF32 swizzled write slot

    float4v acc[MI][NI] = {};
    const float* Af = (const float*)Av;
    const bf16*  Ab = (const bf16*)Av;
    float4v fa0[AP][2], fa1[AP][2], fa2[AP][2];

    const int nt   = K / BKT;
    const int mask = nt - 1;                          // nt is a power of 2
    const int t0   = AF32 ? ((bm * 5 + bn * 3) & mask) : 0;  // K-rotation (AF32 only)
    auto T = [&](int i) { return ((i + t0) & mask) * BKT; };

    auto stage_a = [&](int buf, int kk) {             // bf16 A via DMA (API instrs)
#pragma unroll
        for (int p = 0; p < API; p++) {
            int rbase = wave * (TBM / 4) + p * RPI;
            gload_lds16(Ab + (size_t)(bm * TBM + rbase + srow) * K + kk + kslot * 8,
                        As + buf * ASZ + rbase * BKT + lane * 8);
        }
    };
    auto stage_b = [&](int buf, int kk) {             // bf16 B via DMA (BPI instrs)
#pragma unroll
        for (int p = 0; p < BPI; p++) {
            int rbase = wave * (TBN / 4) + p * RPI;
            gload_lds16(BT + (size_t)(bn * TBN + rbase + srow) * K + kk + kslot * 8,
                        Bs + buf * BSZ + rbase * BKT + lane * 8);
        }
    };
    auto load_a_f32 = [&](float4v (&fa)[AP][2], int kk) {  // fp32 A -> regs (AI loads)
#pragma unroll
        for (int p = 0; p < AP; p++) {
            const float* src = Af + (size_t)(bm * TBM + p * 64 + sr) * K + kk + scs * 8;
            fa[p][0] = *(const float4v*)src;
            fa[p][1] = *(const float4v*)(src + 4);
        }
    };
    auto write_a_f32 = [&](float4v (&fa)[AP][2], int buf) {  // regs -> LDS (swizzled)
#pragma unroll
        for (int p = 0; p < AP; p++)
            *(ushort8v*)(As + buf * ASZ + (p * 64 + sr) * BKT + swslot * 8)
                = cvt8(fa[p][0], fa[p][1]);
    };
    auto compute = [&](int buf) {                     // AF32 path only
#pragma unroll
        for (int h = 0; h < BKT / 32; h++) {
            const int s = (BKT == 32) ? (quad ^ ((l15 >> 1) & 3))
                                      : ((quad + 4 * h) ^ (l15 & 7));
            bf16x8 af[MI], bfr[NI];
#pragma unroll
            for (int mi = 0; mi < MI; mi++)
                af[mi] = *(const bf16x8*)(As + buf * ASZ + (wm + mi * 16 + l15) * BKT + s * 8);
#pragma unroll
            for (int ni = 0; ni < NI; ni++)
                bfr[ni] = *(const bf16x8*)(Bs + buf * BSZ + (wn + ni * 16 + l15) * BKT + s * 8);
            __builtin_amdgcn_s_setprio(1);
#pragma unroll
            for (int mi = 0; mi < MI; mi++)
#pragma unroll
                for (int ni = 0; ni < NI; ni++)
                    acc[mi][ni] = __builtin_amdgcn_mfma_f32_16x16x32_bf16(
                        bfr[ni], af[mi], acc[mi][ni], 0, 0, 0);
            __builtin_amdgcn_s_setprio(0);
        }
    };

    if constexpr (AF32) {
        // depth-3 prologue: A(0..2)->regs, B(0..2)->bufs
        load_a_f32(fa0, T(0)); stage_b(0, T(0));
        load_a_f32(fa1, T(1)); stage_b(1, T(1));
        load_a_f32(fa2, T(2)); stage_b(2, T(2));
        vmwait<2 * AI + 3 * BPI>();       // A(0) landed (B0..B2, A1, A2 in flight)
        write_a_f32(fa0, 0);

        // body(t): compute buf, prefetch tile t+3, cvt+write A(t+1) into nbuf
        auto body = [&](int t, int bi, int nbuf,
                        float4v (&fcur)[AP][2], float4v (&fnext)[AP][2]) {
            int k = nt - 1 - t;               // tiles still in flight at top
            if (k >= 2)      vmwait_lgkm0<2 * (AI + BPI)>();
            else if (k == 1) vmwait_lgkm0<AI + BPI>();
            else             vmwait_lgkm0<0>();
            bar();
            compute(bi);
            bar();
            if (t + 3 < nt) { load_a_f32(fcur, T(t + 3)); stage_b(bi, T(t + 3)); }
            if (t + 1 < nt) {
                if (t + 3 < nt)      vmwait<2 * AI + 3 * BPI>();
                else if (t + 2 < nt) vmwait<AI + 2 * BPI>();
                else                 vmwait<BPI>();
                write_a_f32(fnext, nbuf);
            }
        };
        int t = 0;
        for (; t + 3 <= nt; t += 3) {
            body(t,     0, 1, fa0, fa1);
            body(t + 1, 1, 2, fa1, fa2);
            body(t + 2, 2, 0, fa2, fa0);
        }
        if (t < nt)     body(t,     0, 1, fa0, fa1);
        if (t + 1 < nt) body(t + 1, 1, 2, fa1, fa2);
    } else {
        // bf16 path: depth-3 ring, ONE barrier per iter, stage inside compute
        stage_a(0, 0);     stage_b(0, 0);
        stage_a(1, BKT);   stage_b(1, BKT);
        auto body3 = [&](int t, int bi, int nb) {
            if (t == nt - 1) vmwait<0>(); else vmwait<API + BPI>();
            bar();
#pragma unroll
            for (int h = 0; h < BKT / 32; h++) {
                const int s = (BKT == 32) ? (quad ^ ((l15 >> 1) & 3))
                                          : ((quad + 4 * h) ^ (l15 & 7));
                bf16x8 af[MI], bfr[NI];
#pragma unroll
                for (int mi = 0; mi < MI; mi++)
                    af[mi] = *(const bf16x8*)(As + bi * ASZ + (wm + mi * 16 + l15) * BKT + s * 8);
                if (h == 0 && t + 2 < nt) stage_a(nb, (t + 2) * BKT);
#pragma unroll
                for (int ni = 0; ni < NI; ni++)
                    bfr[ni] = *(const bf16x8*)(Bs + bi * BSZ + (wn + ni * 16 + l15) * BKT + s * 8);
                if (h == 0 && t + 2 < nt) stage_b(nb, (t + 2) * BKT);
                __builtin_amdgcn_s_setprio(1);
#pragma unroll
                for (int mi = 0; mi < MI; mi++)
#pragma unroll
                    for (int ni = 0; ni < NI; ni++)
                        acc[mi][ni] = __builtin_amdgcn_mfma_f32_16x16x32_bf16(
                            bfr[ni], af[mi], acc[mi][ni], 0, 0, 0);
                __builtin_amdgcn_s_setprio(0);
            }
        };
        int t = 0;
        for (; t + 3 <= nt; t += 3) {
            body3(t,     0, 2);
            body3(t + 1, 1, 0);
            body3(t + 2, 2, 1);
        }
        if (t < nt)     body3(t,     0, 2);
        if (t + 1 < nt) body3(t + 1, 1, 0);
    }

    // Swapped layout: row(M) = l15-based, cols = quad*4 + reg (4 consecutive)
#pragma unroll
    for (int mi = 0; mi < MI; mi++) {
#pragma unroll
        for (int ni = 0; ni < NI; ni++) {
            int row = bm * TBM + wm + mi * 16 + l15;
            int col = bn * TBN + wn + ni * 16 + quad * 4;
            float4v v = acc[mi][ni];
            if (EPI == 0) {
                store4bf(o0 + (size_t)row * N + col, v);
            } else if (EPI == 1) {
                int sel = col >> 8, d = col & 255;
                bf16* dst = (sel == 0) ? o0 : (sel == 1) ? o1 : (sel == 2) ? o2 : o3;
                if (sel & 1) {   // gate = o * z
                    float4v z4 = load4bf(auxb + (size_t)row * DI_ + d);
#pragma unroll
                    for (int i = 0; i < 4; i++) v[i] *= z4[i];
                } else {         // delta = sigmoid(o)
#pragma unroll
                    for (int i = 0; i < 4; i++) v[i] = 1.f / (1.f + __expf(-v[i]));
                }
                store4bf(dst + (size_t)row * DI_ + d, v);
            } else {
                float4v r = *(const float4v*)(auxf + (size_t)row * N + col);
#pragma unroll
                for (int i = 0; i < 4; i++) v[i] += r[i];
                store4bf(o0 + (size_t)row * N + col, v);
            }
        }
    }
}

// ---------------------------------------------------------------------------
// Chunked linear-recurrence scan: h_t = delta_t * h_{t-1} + gate_t
// blockIdx.z = direction (0 fwd, 1 bwd/reversed)
// ---------------------------------------------------------------------------
__global__ __launch_bounds__(256) void scan_agg(const bf16* __restrict__ del_f,
                                                const bf16* __restrict__ gat_f,
                                                const bf16* __restrict__ del_b,
                                                const bf16* __restrict__ gat_b,
                                                float* __restrict__ aggA,
                                                float* __restrict__ aggB) {
    int c = blockIdx.x, b = blockIdx.y, dir = blockIdx.z, d = threadIdx.x;
    const bf16* delta = dir ? del_b : del_f;
    const bf16* gate  = dir ? gat_b : gat_f;
    float Ap = 1.f, h = 0.f;
    for (int i = 0; i < LC; i++) {
        int t = dir ? (L_ - 1 - (c * LC + i)) : (c * LC + i);
        size_t base = ((size_t)(b * L_ + t)) * DI_ + d;
        float dlt = bf2f(delta[base]);
        float g   = bf2f(gate[base]);
        Ap *= dlt;
        h = h * dlt + g;
    }
    size_t idx = (((size_t)dir * B_ + b) * NC + c) * DI_ + d;
    aggA[idx] = Ap;
    aggB[idx] = h;
}

__global__ void scan_mid(const float* __restrict__ aggA, const float* __restrict__ aggB,
                         float* __restrict__ Hin) {
    int b = blockIdx.x, dir = blockIdx.y, d = threadIdx.x;
    float h = 0.f;
    for (int c = 0; c < NC; c++) {
        size_t idx = (((size_t)dir * B_ + b) * NC + c) * DI_ + d;
        Hin[idx] = h;
        h = aggA[idx] * h + aggB[idx];
    }
}

__global__ __launch_bounds__(256) void scan_fix(const bf16* __restrict__ del_f,
                                                const bf16* __restrict__ gat_f,
                                                const bf16* __restrict__ del_b,
                                                const bf16* __restrict__ gat_b,
                                                const float* __restrict__ Hin,
                                                bf16* __restrict__ hcat) {
    int c = blockIdx.x, b = blockIdx.y, dir = blockIdx.z, d = threadIdx.x;
    const bf16* delta = dir ? del_b : del_f;
    const bf16* gate  = dir ? gat_b : gat_f;
    float h = Hin[(((size_t)dir * B_ + b) * NC + c) * DI_ + d];
    int colbase = dir * DI_;
    for (int i = 0; i < LC; i++) {
        int t = dir ? (L_ - 1 - (c * LC + i)) : (c * LC + i);
        size_t base = ((size_t)(b * L_ + t)) * DI_ + d;
        float dlt = bf2f(delta[base]);
        float g   = bf2f(gate[base]);
        h = h * dlt + g;
        hcat[((size_t)(b * L_ + t)) * (2 * DI_) + colbase + d] = f2bf(h);
    }
}

// ---------------------------------------------------------------------------
// LayerNorm over D=2048: reads bf16 ybuf, writes fp32 out. Fully vectorized.
// ---------------------------------------------------------------------------
__global__ __launch_bounds__(256) void ln_kernel(const bf16* __restrict__ y,
                                                 const float* __restrict__ gamma,
                                                 const float* __restrict__ beta,
                                                 float* __restrict__ outp) {
    __shared__ float ss[4], ssq[4];
    int row = blockIdx.x, tid = threadIdx.x;
    size_t base = (size_t)row * D_ + tid * 8;
    uint4 raw = *(const uint4*)(y + base);
    const unsigned short* u = (const unsigned short*)&raw;
    float v[8];
    float s = 0.f, sq = 0.f;
#pragma unroll
    for (int i = 0; i < 8; i++) {
        v[i] = __uint_as_float(((unsigned)u[i]) << 16);
        s += v[i];
        sq += v[i] * v[i];
    }
    for (int o = 32; o > 0; o >>= 1) { s += __shfl_down(s, o); sq += __shfl_down(sq, o); }
    if ((tid & 63) == 0) { ss[tid >> 6] = s; ssq[tid >> 6] = sq; }
    __syncthreads();
    float S  = ss[0] + ss[1] + ss[2] + ss[3];
    float SQ = ssq[0] + ssq[1] + ssq[2] + ssq[3];
    float mean = S * (1.f / D_);
    float var  = SQ * (1.f / D_) - mean * mean;
    float rstd = rsqrtf(var + 1e-5f);
    float4v g0 = *(const float4v*)(gamma + tid * 8);
    float4v g1 = *(const float4v*)(gamma + tid * 8 + 4);
    float4v b0 = *(const float4v*)(beta + tid * 8);
    float4v b1 = *(const float4v*)(beta + tid * 8 + 4);
    float4v r0, r1;
#pragma unroll
    for (int i = 0; i < 4; i++) {
        r0[i] = (v[i] - mean) * rstd * g0[i] + b0[i];
        r1[i] = (v[i + 4] - mean) * rstd * g1[i] + b1[i];
    }
    *(float4v*)(outp + base)     = r0;
    *(float4v*)(outp + base + 4) = r1;
}

// ---------------------------------------------------------------------------
extern "C" void kernel_launch(void* const* d_in, const int* in_sizes, int n_in,
                              void* d_out, int out_size, void* d_ws, size_t ws_size,
                              hipStream_t stream) {
    (void)in_sizes; (void)n_in; (void)out_size; (void)ws_size;
    const float* x     = (const float*)d_in[0];
    const float* W_in  = (const float*)d_in[1];
    const float* W_fwd = (const float*)d_in[2];
    const float* W_bwd = (const float*)d_in[3];
    const float* W_out = (const float*)d_in[4];
    const float* gamma = (const float*)d_in[5];
    const float* beta  = (const float*)d_in[6];
    float* out = (float*)d_out;

    char* ws = (char*)d_ws;
    size_t off = 0;
    auto alloc = [&](size_t bytes) -> char* {
        char* p = ws + off;
        off += (bytes + 255) & ~(size_t)255;
        return p;
    };
    bf16*  WinT   = (bf16*)alloc((size_t)DI_ * D_ * 2);           // [256, 2048]
    bf16*  WpT    = (bf16*)alloc((size_t)1024 * DI_ * 2);         // [1024, 256] fwd|bwd
    bf16*  WoutT  = (bf16*)alloc((size_t)D_ * 2 * DI_ * 2);       // [2048, 512]
    bf16*  z      = (bf16*)alloc((size_t)M_ * DI_ * 2);
    bf16*  del_f  = (bf16*)alloc((size_t)M_ * DI_ * 2);
    bf16*  gat_f  = (bf16*)alloc((size_t)M_ * DI_ * 2);
    bf16*  del_b  = (bf16*)alloc((size_t)M_ * DI_ * 2);
    bf16*  gat_b  = (bf16*)alloc((size_t)M_ * DI_ * 2);
    bf16*  hcat   = (bf16*)alloc((size_t)M_ * 2 * DI_ * 2);       // 16.8 MB
    bf16*  ybuf   = (bf16*)alloc((size_t)M_ * D_ * 2);            // 67 MB
    float* aggA   = (float*)alloc((size_t)2 * B_ * NC * DI_ * 4);
    float* aggB   = (float*)alloc((size_t)2 * B_ * NC * DI_ * 4);
    float* Hin    = (float*)alloc((size_t)2 * B_ * NC * DI_ * 4);

    // 1. fused weight transposes (fp32 -> bf16 [N,K]) — one launch
    constexpr int TTOT = D_ * DI_ + 2 * DI_ * 2 * DI_ + 2 * DI_ * D_;
    transpose_all<<<(TTOT + 255) / 256, 256, 0, stream>>>(
        W_in, W_fwd, W_bwd, W_out, WinT, WpT, WoutT);

    // 2. GEMM1: z = x @ W_in  [16384 x 2048] x [2048 x 256], fp32 A reg-staged.
    //    <64,128> grid (256,2) -> 2 blocks/CU; depth-3 pipeline; K-rotation.
    gemm_bt<64, 128, 32, 0, true><<<dim3(M_ / 64, 2), 256, 0, stream>>>(
        x, WinT, D_, DI_, z, nullptr, nullptr, nullptr, nullptr, nullptr);

    // 3. GEMM2 fused dirs: o = z @ [W_fwd|W_bwd]; delta=sigmoid, gate=o*z.
    //    depth-3 ring, 1 barrier/iter.
    gemm_bt<128, 128, 32, 1, false><<<dim3(M_ / 128, 1024 / 128), 256, 0, stream>>>(
        z, WpT, DI_, 1024, del_f, gat_f, del_b, gat_b, z, nullptr);

    // 4. chunked scans (dir in blockIdx.z), write concat [h_f|h_b]
    scan_agg<<<dim3(NC, B_, 2), DI_, 0, stream>>>(del_f, gat_f, del_b, gat_b, aggA, aggB);
    scan_mid<<<dim3(B_, 2), DI_, 0, stream>>>(aggA, aggB, Hin);
    scan_fix<<<dim3(NC, B_, 2), DI_, 0, stream>>>(del_f, gat_f, del_b, gat_b, Hin, hcat);

    // 5. GEMM3: y = hcat @ W_out + x  [16384 x 512] x [512 x 2048] -> ybuf bf16.
    //    depth-3 ring, 1 barrier/iter.
    gemm_bt<128, 128, 32, 2, false><<<dim3(M_ / 128, D_ / 128), 256, 0, stream>>>(
        hcat, WoutT, 2 * DI_, D_, ybuf, nullptr, nullptr, nullptr, nullptr, x);

    // 6. LayerNorm: ybuf -> fp32 out
    ln_kernel<<<M_, 256, 0, stream>>>(ybuf, gamma, beta, out);
}